// Round 6
// baseline (5893.428 us; speedup 1.0000x reference)
//
#include <hip/hip_runtime.h>

#define TT 2000
#define NN 512
#define MM 64
#define ALPHA 0.2f   // DT/TAU

typedef unsigned long long u64;

// DPP row_ror butterfly reduce within 16-lane rows (VALU pipe, not LDS).
// Rotate-and-add by 1,2,4,8: EVERY lane of the row ends with the 16-lane sum.
#define DPP_ROR_ADD(v, ctrl) do { \
  int _t = __builtin_amdgcn_update_dpp(0, __float_as_int(v), (ctrl), 0xF, 0xF, true); \
  (v) += __int_as_float(_t); } while (0)
#define ROW_REDUCE16(v) do { \
  DPP_ROR_ADD(v, 0x121); DPP_ROR_ADD(v, 0x122); \
  DPP_ROR_ADD(v, 0x124); DPP_ROR_ADD(v, 0x128); } while (0)

__device__ __forceinline__ float hsum4(float4 a){ return (a.x + a.y) + (a.z + a.w); }

// 256 blocks (1/CU, co-resident): bid = p*64 + r; block owns neurons
// [p*128, p*128+128) of batch row r. 512 thr: group g = tid>>4 owns 4 neurons,
// l16 = tid&15 owns K-chunks {jj*64 + l16*4 .. +3 : jj=0..7}.
// Weights: 32 float4 = 128 VGPR/thread, PINNED in registers via asm opacity
// (round-5 counters proved the compiler re-loads them from L2 every step at
// VGPR=120 -> 24.5 TB/s L2 streaming, the then-bottleneck). One __syncthreads
// per step; cross-block u exchange via tagged 8B relaxed agent-scope packets.
__global__ __launch_bounds__(512, 2) void ctrnn(
    const float* __restrict__ I, const float* __restrict__ x0,
    const float* __restrict__ W_in, const float* __restrict__ W_rec,
    const float* __restrict__ b,
    float* __restrict__ out_x, float* __restrict__ out_u,
    u64* __restrict__ pkt, float* __restrict__ uT)
{
  __shared__ float u_lds[2][16 * 36];     // u[k] at (k>>5)*36 + (k&31); parity-buffered
  __shared__ float xbuf[2][128 * 9];      // octet-parity staging, stride-9 pad
  __shared__ float ubuf[2][128 * 9];

  const int p = blockIdx.x >> 6, r = blockIdx.x & 63;
  const int tid = threadIdx.x;
  const int g = tid >> 4, l16 = tid & 15;
  const int nb = p * 128 + g * 4;

  // ---- weights into registers, coalesced (16 lanes x 16B = 256B/row-pass) ----
  float4 w[4][8];
  #pragma unroll
  for (int rr = 0; rr < 4; rr++)
    #pragma unroll
    for (int jj = 0; jj < 8; jj++)
      w[rr][jj] = *(const float4*)(W_rec + (size_t)(nb + rr) * NN + jj * 64 + l16 * 4);
  // Opacity pin: values become asm-defined -> compiler cannot re-materialize
  // the global loads inside the loop; must hold 128 VGPRs live.
  #pragma unroll
  for (int rr = 0; rr < 4; rr++)
    #pragma unroll
    for (int jj = 0; jj < 8; jj++)
      asm volatile("" : "+v"(w[rr][jj].x), "+v"(w[rr][jj].y),
                        "+v"(w[rr][jj].z), "+v"(w[rr][jj].w));

  const bool owner = (l16 == 0);          // updates neurons nb..nb+3
  float wi0[4], wi1[4], bb[4], xs[4], us[4];
  const float x00 = x0[0];
  const float u00 = tanhf(x00);
  #pragma unroll
  for (int j = 0; j < 4; j++){ xs[j] = x00; us[j] = u00; wi0[j] = wi1[j] = bb[j] = 0.f; }
  if (owner){
    #pragma unroll
    for (int j = 0; j < 4; j++){
      wi0[j] = W_in[2 * (nb + j)]; wi1[j] = W_in[2 * (nb + j) + 1]; bb[j] = b[nb + j];
    }
  }

  u_lds[0][(tid >> 5) * 36 + (tid & 31)] = u00;   // u_0, buffer 0
  __syncthreads();

  const float* Ib = I + (size_t)r * 2 * TT;
  float* ox = out_x + (size_t)r * NN * TT;
  float* ou = out_u + (size_t)r * NN * TT;
  u64* pr = pkt + (size_t)r * NN;
  const int q  = tid - 128;                                  // poller id
  const int rn = (q < p * 128) ? q : q + 128;                // remote neuron (q>=0)

  for (int t = 0; t < TT; t++){
    const int cbuf = t & 1, nbuf = cbuf ^ 1;
    const int oct = (t >> 3) & 1, p8 = t & 7;

    // 0. early input loads (latency hidden under matvec)
    float i0 = 0.f, i1 = 0.f;
    if (owner){ i0 = Ib[t]; i1 = Ib[TT + t]; }

    // 1. stage pre-step x,u
    if (owner){
      #pragma unroll
      for (int j = 0; j < 4; j++){
        xbuf[oct][(g * 4 + j) * 9 + p8] = xs[j];
        ubuf[oct][(g * 4 + j) * 9 + p8] = us[j];
      }
    }

    // 2. main matvec: 4 neurons x 32 k per thread over u_t
    //    k = jj*64 + l16*4 + c  ->  u_lds row jj*2 + (l16>>3), col (l16&7)*4
    float s[4];
    {
      const float* ub = u_lds[cbuf];
      float4 a0 = make_float4(0,0,0,0), a1 = a0, a2 = a0, a3 = a0;
      #pragma unroll
      for (int jj = 0; jj < 8; jj++){
        float4 uv = *(const float4*)(ub + (jj * 2 + (l16 >> 3)) * 36 + (l16 & 7) * 4);
        a0.x = fmaf(w[0][jj].x, uv.x, a0.x); a0.y = fmaf(w[0][jj].y, uv.y, a0.y);
        a0.z = fmaf(w[0][jj].z, uv.z, a0.z); a0.w = fmaf(w[0][jj].w, uv.w, a0.w);
        a1.x = fmaf(w[1][jj].x, uv.x, a1.x); a1.y = fmaf(w[1][jj].y, uv.y, a1.y);
        a1.z = fmaf(w[1][jj].z, uv.z, a1.z); a1.w = fmaf(w[1][jj].w, uv.w, a1.w);
        a2.x = fmaf(w[2][jj].x, uv.x, a2.x); a2.y = fmaf(w[2][jj].y, uv.y, a2.y);
        a2.z = fmaf(w[2][jj].z, uv.z, a2.z); a2.w = fmaf(w[2][jj].w, uv.w, a2.w);
        a3.x = fmaf(w[3][jj].x, uv.x, a3.x); a3.y = fmaf(w[3][jj].y, uv.y, a3.y);
        a3.z = fmaf(w[3][jj].z, uv.z, a3.z); a3.w = fmaf(w[3][jj].w, uv.w, a3.w);
      }
      s[0] = hsum4(a0); s[1] = hsum4(a1); s[2] = hsum4(a2); s[3] = hsum4(a3);
      ROW_REDUCE16(s[0]); ROW_REDUCE16(s[1]); ROW_REDUCE16(s[2]); ROW_REDUCE16(s[3]);
    }

    // 3. owner: Euler update, tanh, publish u_{t+1} (LDS + tagged packets)
    if (owner){
      #pragma unroll
      for (int j = 0; j < 4; j++){
        float pre = s[j] + fmaf(wi0[j], i0, fmaf(wi1[j], i1, bb[j]));
        xs[j] = fmaf(ALPHA, pre - xs[j], xs[j]);     // x + a*(pre-x)
        us[j] = tanhf(xs[j]);
      }
      *(float4*)(u_lds[nbuf] + (nb >> 5) * 36 + (nb & 31)) =
          make_float4(us[0], us[1], us[2], us[3]);
      const u64 tagw = ((u64)(unsigned)(t + 1)) << 32;
      u64* pd = pr + (size_t)nbuf * (MM * NN) + nb;
      #pragma unroll
      for (int j = 0; j < 4; j++)
        __hip_atomic_store(pd + j, tagw | (u64)__float_as_uint(us[j]),
                           __ATOMIC_RELAXED, __HIP_MEMORY_SCOPE_AGENT);
    }
    asm volatile("" ::: "memory");   // pin store-before-poll (deadlock safety)

    // 4. pollers: gather remote u_{t+1}
    if (q >= 0){
      u64* ps = pr + (size_t)nbuf * (MM * NN) + rn;
      u64 pk = __hip_atomic_load(ps, __ATOMIC_RELAXED, __HIP_MEMORY_SCOPE_AGENT);
      while ((unsigned)(pk >> 32) != (unsigned)(t + 1)){
        __builtin_amdgcn_s_sleep(1);
        pk = __hip_atomic_load(ps, __ATOMIC_RELAXED, __HIP_MEMORY_SCOPE_AGENT);
      }
      u_lds[nbuf][(rn >> 5) * 36 + (rn & 31)] = __uint_as_float((unsigned)pk);
    }

    // 5. flush previous x,u octet (coalesced float4, separated by 8 barriers)
    if (p8 == 0 && t > 0){
      const int arr = tid >> 8, n2 = (tid >> 1) & 127, h = tid & 1;
      const float* src = (arr ? ubuf[oct ^ 1] : xbuf[oct ^ 1]) + n2 * 9 + 4 * h;
      float* dst = (arr ? ou : ox) + (size_t)(p * 128 + n2) * TT + (t - 8) + 4 * h;
      *(float4*)dst = make_float4(src[0], src[1], src[2], src[3]);
    }

    __syncthreads();   // single barrier: u_{t+1} visible for next matvec
  }

  // ---- epilogue: final x/u octet flush + u_T side-buffer for the y-kernel ----
  {
    const int arr = tid >> 8, n2 = (tid >> 1) & 127, h = tid & 1;
    const float* src = (arr ? ubuf[1] : xbuf[1]) + n2 * 9 + 4 * h;
    float* dst = (arr ? ou : ox) + (size_t)(p * 128 + n2) * TT + (TT - 8) + 4 * h;
    *(float4*)dst = make_float4(src[0], src[1], src[2], src[3]);
  }
  if (owner)
    *(float4*)(uT + (size_t)r * NN + nb) = make_float4(us[0], us[1], us[2], us[3]);
}

// y[m][c][t] = sum_n W_out[c][n] * u_{t+1}[m][n]; u_{t+1} = out_u[...,t+1]
// for t < T-1, else the uT side-buffer. One block per (m, 256-t chunk);
// thread t streams n with wave-coalesced reads (64 consecutive t per row).
__global__ __launch_bounds__(256) void y_out(
    const float* __restrict__ W_out, const float* __restrict__ ou,
    const float* __restrict__ uT, float* __restrict__ oy)
{
  __shared__ float w0[NN], w1[NN];
  const int m = blockIdx.x, tid = threadIdx.x;
  for (int i = tid; i < NN; i += 256){ w0[i] = W_out[i]; w1[i] = W_out[NN + i]; }
  __syncthreads();
  const int t = blockIdx.y * 256 + tid;
  if (t >= TT) return;
  float acc0 = 0.f, acc1 = 0.f;
  if (t + 1 < TT){
    const float* um = ou + (size_t)m * NN * TT + (t + 1);
    #pragma unroll 4
    for (int n = 0; n < NN; n++){
      float uv = um[(size_t)n * TT];
      acc0 = fmaf(w0[n], uv, acc0); acc1 = fmaf(w1[n], uv, acc1);
    }
  } else {
    const float* um = uT + (size_t)m * NN;
    #pragma unroll 4
    for (int n = 0; n < NN; n++){
      float uv = um[n];
      acc0 = fmaf(w0[n], uv, acc0); acc1 = fmaf(w1[n], uv, acc1);
    }
  }
  oy[(size_t)m * 2 * TT + t]      = acc0;
  oy[(size_t)m * 2 * TT + TT + t] = acc1;
}

extern "C" void kernel_launch(void* const* d_in, const int* in_sizes, int n_in,
                              void* d_out, int out_size, void* d_ws, size_t ws_size,
                              hipStream_t stream){
  const float* I     = (const float*)d_in[0];
  const float* x0    = (const float*)d_in[1];
  const float* W_in  = (const float*)d_in[2];
  const float* W_rec = (const float*)d_in[3];
  const float* b     = (const float*)d_in[4];
  const float* W_out = (const float*)d_in[5];

  float* out_x = (float*)d_out;
  float* out_u = out_x + (size_t)MM * NN * TT;
  float* out_y = out_u + (size_t)MM * NN * TT;
  u64*   pkt   = (u64*)d_ws;                       // 512 KB; 0xAA poison never matches tags
  float* uT    = (float*)((char*)d_ws + (size_t)2 * MM * NN * sizeof(u64));  // +128 KB

  ctrnn<<<MM * 4, 512, 0, stream>>>(I, x0, W_in, W_rec, b,
                                    out_x, out_u, pkt, uT);
  dim3 gy(MM, (TT + 255) / 256);
  y_out<<<gy, 256, 0, stream>>>(W_out, out_u, uT, out_y);
}